// Round 8
// baseline (453.441 us; speedup 1.0000x reference)
//
#include <hip/hip_runtime.h>
#include <cstdint>
#include <cstddef>

#pragma clang fp contract(off)

constexpr int NIMG  = 16;
constexpr int NB0   = 19200;   // 80*80*3
constexpr int NB1   = 4800;    // 40*40*3
constexpr int NB2   = 1200;    // 20*20*3
constexpr int NBOX  = 25200;
constexpr int NCLS  = 80;
constexpr int NCH   = 85;
constexpr int NBINS = 4096;
constexpr int CAP   = 4096;
constexpr int NTOP  = 1000;
constexpr int NDET  = 100;
constexpr int WLCAP = 65536;   // worklist capacity (<= NIMG*CAP)
constexpr float IMGSZ = 640.0f;
constexpr float BIN_SCALE = 4096.0f / 0.75f;

constexpr int CHUNK   = 32;            // boxes per LDS chunk (38 KB total LDS -> 4 blocks/CU)
constexpr int CHUNK_F = CHUNK * NCH;   // 2720 floats
constexpr int TILE    = 512;           // boxes per block (16 chunks)
constexpr int TILES   = (NBOX + TILE - 1) / TILE;   // 50

// ---------------- XLA-CPU-matching transcendentals (verified absmax=0) ----------------
__device__ __forceinline__ float xla_expf(float x) {
  const float kLog2e = 1.44269504088896341f;
  const float kC1 = 0.693359375f;
  const float kC2 = -2.12194440e-4f;
  const float cp0 = 1.9875691500e-4f;
  const float cp1 = 1.3981999507e-3f;
  const float cp2 = 8.3334519073e-3f;
  const float cp3 = 4.1665795894e-2f;
  const float cp4 = 1.6666665459e-1f;
  const float cp5 = 5.0000001201e-1f;
  float xc = fminf(x, 88.3762626647950f);
  xc = fmaxf(xc, -88.3762626647949f);
  float fx = floorf(fmaf(xc, kLog2e, 0.5f));
  float xr = fmaf(fx, -kC1, xc);
  xr = fmaf(fx, -kC2, xr);
  float z = xr * xr;
  float y = fmaf(cp0, xr, cp1);
  y = fmaf(y, xr, cp2);
  y = fmaf(y, xr, cp3);
  y = fmaf(y, xr, cp4);
  y = fmaf(y, xr, cp5);
  y = fmaf(y, z, xr);
  y = y + 1.0f;
  int n = (int)fx;
  float two_n = __int_as_float((n + 127) << 23);
  float r = y * two_n;
  return fmaxf(r, xc);
}

__device__ __forceinline__ float ref_sigmoid(float x) {
  return 1.0f / (1.0f + xla_expf(-x));
}

// ---------------- geometry helpers ----------------
__device__ __forceinline__ const float* locate(int img, int box,
    const float* __restrict__ p0, const float* __restrict__ p1, const float* __restrict__ p2,
    int& lvl, int& gx, int& gy, int& anc, float& stride) {
  const float* base; int r, W;
  if (box < NB0)            { lvl = 0; r = box;             W = 80; base = p0 + (size_t)img * NB0 * NCH; stride = 8.0f;  }
  else if (box < NB0 + NB1) { lvl = 1; r = box - NB0;       W = 40; base = p1 + (size_t)img * NB1 * NCH; stride = 16.0f; }
  else                      { lvl = 2; r = box - NB0 - NB1; W = 20; base = p2 + (size_t)img * NB2 * NCH; stride = 32.0f; }
  anc = r % 3;
  int cell = r / 3;
  gx = cell % W;
  gy = cell / W;
  return base + (size_t)r * NCH;
}

__device__ __forceinline__ float clip640(float v) {
  return fminf(fmaxf(v, 0.0f), IMGSZ);
}

// chunk (32 aligned boxes) never straddles a level boundary: 19200, 24000 are multiples of 32
__device__ __forceinline__ const float* chunk_ptr(int img, int first_box,
    const float* __restrict__ p0, const float* __restrict__ p1, const float* __restrict__ p2) {
  const float* base; int r;
  if (first_box < NB0)            { base = p0 + (size_t)img * NB0 * NCH; r = first_box; }
  else if (first_box < NB0 + NB1) { base = p1 + (size_t)img * NB1 * NCH; r = first_box - NB0; }
  else                            { base = p2 + (size_t)img * NB2 * NCH; r = first_box - NB0 - NB1; }
  return base + (size_t)r * NCH;
}

// ---------------- pass A: stream input once, histogram + per-box maxbin ----------------
__global__ __launch_bounds__(256) void k_passA(const float* __restrict__ p0,
    const float* __restrict__ p1, const float* __restrict__ p2,
    unsigned int* __restrict__ ghist, unsigned short* __restrict__ maxbin) {
  __shared__ __align__(16) float buf[2][CHUNK_F];   // 21.76 KB
  __shared__ unsigned int hist[NBINS];              // 16 KB
  const int tid = threadIdx.x;
  const int img  = blockIdx.x / TILES;
  const int tile = blockIdx.x % TILES;
  const int tbase = tile * TILE;
  const int nbox_tile = min(TILE, NBOX - tbase);
  const int nch = (nbox_tile + CHUNK - 1) / CHUNK;

  for (int i = tid; i < NBINS; i += 256) hist[i] = 0u;

  float4 regs[3];
  // prologue: load chunk 0 into buf[0]
  {
    int nb0c = min(CHUNK, nbox_tile);
    const float* cp = chunk_ptr(img, tbase, p0, p1, p2);
    int nv = (nb0c * NCH) / 4;   // <= 680
    const float4* cp4 = (const float4*)cp;
    float4* b4 = (float4*)&buf[0][0];
    #pragma unroll
    for (int k = 0; k < 3; ++k) { int i = tid + k * 256; if (i < nv) regs[k] = cp4[i]; }
    #pragma unroll
    for (int k = 0; k < 3; ++k) { int i = tid + k * 256; if (i < nv) b4[i] = regs[k]; }
  }
  __syncthreads();

  for (int c = 0; c < nch; ++c) {
    int nvN = 0;
    if (c + 1 < nch) {
      int fb = tbase + (c + 1) * CHUNK;
      int nbN = min(CHUNK, NBOX - fb);
      const float* cp = chunk_ptr(img, fb, p0, p1, p2);
      nvN = (nbN * NCH) / 4;
      const float4* cp4 = (const float4*)cp;
      #pragma unroll
      for (int k = 0; k < 3; ++k) { int i = tid + k * 256; if (i < nvN) regs[k] = cp4[i]; }
    }
    {
      int nb = min(CHUNK, nbox_tile - c * CHUNK);
      int b = tid >> 3, part = tid & 7;
      if (b < nb) {
        const float* row = &buf[c & 1][b * NCH];
        float obj = ref_sigmoid(row[4]);
        int mb = 0;
        if (obj > 0.25f) {
          float rr = 0.25f / obj;
          float tcons = __logf(rr / (1.0f - rr)) - 0.01f;   // conservative pre-filter
          #pragma unroll
          for (int cc = 0; cc < 10; ++cc) {
            float x = row[5 + part + 8 * cc];
            if (x > tcons) {
              float s = obj * ref_sigmoid(x);               // exact path
              if (s > 0.25f) {
                int bin = (int)((s - 0.25f) * BIN_SCALE);
                bin = min(bin, NBINS - 1);
                atomicAdd(&hist[bin], 1u);
                mb = max(mb, bin + 1);                      // stored = maxbin+1, 0 = none
              }
            }
          }
        }
        mb = max(mb, __shfl_xor(mb, 1, 8));
        mb = max(mb, __shfl_xor(mb, 2, 8));
        mb = max(mb, __shfl_xor(mb, 4, 8));
        if (part == 0)
          maxbin[(size_t)img * NBOX + tbase + c * CHUNK + b] = (unsigned short)mb;
      }
    }
    if (c + 1 < nch) {
      float4* b4 = (float4*)&buf[(c + 1) & 1][0];
      #pragma unroll
      for (int k = 0; k < 3; ++k) { int i = tid + k * 256; if (i < nvN) b4[i] = regs[k]; }
    }
    __syncthreads();
  }

  for (int i = tid; i < NBINS; i += 256) {
    unsigned int v = hist[i];
    if (v) atomicAdd(&ghist[img * NBINS + i], v);
  }
}

// ---------------- per-image threshold bin (parallel scan, 16 blocks) ----------------
__global__ __launch_bounds__(256) void k_thresh(const unsigned int* __restrict__ ghist,
                                                int* __restrict__ tbin) {
  __shared__ unsigned int h[NBINS];
  __shared__ unsigned int psum[256];
  const int tid = threadIdx.x;
  const int img = blockIdx.x;

  for (int i = tid; i < NBINS; i += 256) h[i] = ghist[img * NBINS + i];
  __syncthreads();
  unsigned int ps = 0;
  for (int k = 0; k < 16; ++k) ps += h[tid * 16 + k];
  psum[tid] = ps;
  __syncthreads();
  if (tid == 0) {
    long long cum = 0;
    int tb = 0;
    bool found = false;
    for (int g = 255; g >= 0 && !found; --g) {
      if (cum + (long long)psum[g] >= NTOP) {
        for (int b = g * 16 + 15; b >= g * 16; --b) {
          cum += h[b];
          if (cum >= NTOP) { tb = b; found = true; break; }
        }
      } else {
        cum += psum[g];
      }
    }
    if (!found) tb = 0;
    while (cum > CAP && tb < NBINS - 1) { cum -= h[tb]; ++tb; }
    tbin[img] = tb;
  }
}

// ---------------- worklist: compact passing rows (dense, coalesced) ----------------
__global__ __launch_bounds__(256) void k_worklist(const unsigned short* __restrict__ maxbin,
    const int* __restrict__ tbin, unsigned int* __restrict__ worklist,
    int* __restrict__ wcnt) {
  __shared__ int lcnt;
  __shared__ int lbase;
  const int tid = threadIdx.x;
  if (tid == 0) lcnt = 0;
  __syncthreads();
  int idx = blockIdx.x * 256 + tid;
  bool pass = false;
  int my = 0;
  int img = 0, box = 0;
  if (idx < NIMG * NBOX) {
    img = idx / NBOX;
    box = idx - img * NBOX;
    int mb = (int)maxbin[idx];
    if (mb > tbin[img]) {            // mb = maxbin+1 > tb  <=>  maxbin >= tb
      pass = true;
      my = atomicAdd(&lcnt, 1);
    }
  }
  __syncthreads();
  if (tid == 0 && lcnt > 0) lbase = atomicAdd(wcnt, lcnt);
  __syncthreads();
  if (pass) {
    int pos = lbase + my;
    if (pos < WLCAP) worklist[pos] = ((unsigned int)img << 16) | (unsigned int)box;
  }
}

// ---------------- emit: one dense row per thread, exact keys ----------------
__global__ __launch_bounds__(256) void k_emit(const float* __restrict__ p0,
    const float* __restrict__ p1, const float* __restrict__ p2,
    const unsigned int* __restrict__ worklist, const int* __restrict__ wcnt,
    const int* __restrict__ tbin, unsigned long long* __restrict__ cand,
    int* __restrict__ cnt) {
  int n = *wcnt;
  if (n > WLCAP) n = WLCAP;
  const int nthreads = gridDim.x * 256;
  for (int i = blockIdx.x * 256 + threadIdx.x; i < n; i += nthreads) {
    unsigned int e = worklist[i];
    int img = (int)(e >> 16);
    int box = (int)(e & 0xFFFFu);
    int lvl, gx, gy, anc; float stride;
    const float* ptr = locate(img, box, p0, p1, p2, lvl, gx, gy, anc, stride);
    float obj = ref_sigmoid(ptr[4]);
    if (obj <= 0.25f) continue;
    int tb = tbin[img];
    float rr = 0.25f / obj;
    float tcons = __logf(rr / (1.0f - rr)) - 0.01f;
    #pragma unroll 8
    for (int c = 0; c < NCLS; ++c) {
      float x = ptr[5 + c];
      if (x <= tcons) continue;
      float s = obj * ref_sigmoid(x);
      if (s > 0.25f) {
        int bin = (int)((s - 0.25f) * BIN_SCALE);
        bin = min(bin, NBINS - 1);
        if (bin >= tb) {
          int pos = atomicAdd(&cnt[img], 1);
          if (pos < CAP) {
            unsigned int fi = (unsigned int)(box * NCLS + c);
            unsigned long long key =
                ((unsigned long long)__float_as_uint(s) << 32) |
                (unsigned long long)(0xFFFFFFFFu - fi);
            cand[(size_t)img * CAP + pos] = key;
          }
        }
      }
    }
  }
}

// ---------------- sort + decode top-1000 into boxes8 (one block per image) ----------------
// swizzled LDS index: pad every 16 u64 keys to break the i/i+16 bank aliasing
#define SIDX(i) ((i) + ((i) >> 4))

__global__ __launch_bounds__(256) void k_sort(const float* __restrict__ p0,
    const float* __restrict__ p1, const float* __restrict__ p2,
    const float* __restrict__ anchors, const unsigned long long* __restrict__ cand,
    const int* __restrict__ cnt_arr, float* __restrict__ boxes8) {
  __shared__ unsigned long long keys[CAP + CAP / 16];   // 34.8 KB (swizzled)
  __shared__ int n2_sh, cnt_sh;
  const int tid = threadIdx.x;
  const int img = blockIdx.x;

  if (tid == 0) {
    int c = cnt_arr[img];
    c = max(0, min(c, CAP));
    int n2 = 1024;
    while (n2 < c) n2 <<= 1;
    cnt_sh = c; n2_sh = n2;
  }
  __syncthreads();
  const int cnt = cnt_sh;
  const int n2  = n2_sh;

  const unsigned long long* c = cand + (size_t)img * CAP;
  for (int i = tid; i < n2; i += 256) keys[SIDX(i)] = (i < cnt) ? c[i] : 0ull;
  __syncthreads();

  for (int kk = 2; kk <= n2; kk <<= 1) {
    for (int j = kk >> 1; j > 0; j >>= 1) {
      for (int i = tid; i < n2; i += 256) {
        int l = i ^ j;
        if (l > i) {
          unsigned long long a = keys[SIDX(i)], b = keys[SIDX(l)];
          bool up = ((i & kk) == 0);
          bool sw = up ? (a < b) : (a > b);
          if (sw) { keys[SIDX(i)] = b; keys[SIDX(l)] = a; }
        }
      }
      __syncthreads();
    }
  }

  // decode top-1000 -> boxes8[img][1000][8] = {b0,b1,b2,b3,val,label,0,0}
  float* dst = boxes8 + (size_t)img * NTOP * 8;
  for (int i = tid; i < NTOP; i += 256) {
    unsigned long long key = keys[SIDX(i)];
    unsigned int v = (unsigned int)(key >> 32);
    float4 fa, fb;
    if (v) {
      unsigned int idx = 0xFFFFFFFFu - (unsigned int)(key & 0xFFFFFFFFu);
      int box = (int)(idx / NCLS);
      int l   = (int)(idx % NCLS);
      int lvl, gx, gy, anc; float stride;
      const float* ptr = locate(img, box, p0, p1, p2, lvl, gx, gy, anc, stride);
      float sx = ref_sigmoid(ptr[0]);
      float sy = ref_sigmoid(ptr[1]);
      float sw = ref_sigmoid(ptr[2]);
      float sh = ref_sigmoid(ptr[3]);
      float aw = anchors[(lvl * 3 + anc) * 2 + 0];
      float ah = anchors[(lvl * 3 + anc) * 2 + 1];
      float cx = (2.0f * sx - 0.5f + (float)gx) * stride;
      float cy = (2.0f * sy - 0.5f + (float)gy) * stride;
      float ww = (4.0f * (sw * sw)) * aw;
      float hh = (4.0f * (sh * sh)) * ah;
      fa.x = clip640(cx - ww * 0.5f);
      fa.y = clip640(cy - hh * 0.5f);
      fa.z = clip640(cx + ww * 0.5f);
      fa.w = clip640(cy + hh * 0.5f);
      fb.x = __uint_as_float(v);
      fb.y = (float)l;
      fb.z = 0.0f; fb.w = 0.0f;
    } else {
      fa.x = fa.y = fa.z = fa.w = 0.0f;
      fb.x = 0.0f; fb.y = -1.0f; fb.z = 0.0f; fb.w = 0.0f;
    }
    *(float4*)(dst + i * 8)     = fa;
    *(float4*)(dst + i * 8 + 4) = fb;
  }
}

// ---------------- NMS: one wave per image, interleaved ownership ----------
// Lane l owns entries t = k*64 + l (k<16). LDS reads at t=k*64+l hit bank l%32
// -> exactly 2 lanes/bank (free per m136). Boxes stay in LDS (no 80-reg/lane
// array, no spill); only labels (16 ints) + alive mask live in registers.
// First-alive selection: lowest k with nonzero ballot, then lowest lane
// == min t == first entry in sorted order == ref's argmax tie-break.
__global__ __launch_bounds__(64) void k_nms(const float* __restrict__ boxes8,
    const float* __restrict__ scalef, float* __restrict__ out) {
  __shared__ float b0a[1024], b1a[1024], b2a[1024], b3a[1024], va_s[1024];
  __shared__ int la_s[1024];
  const int l = threadIdx.x;
  const int img = blockIdx.x;
  const float* src = boxes8 + (size_t)img * NTOP * 8;

  int rlab[16];
  unsigned int amask = 0u;
  #pragma unroll
  for (int k = 0; k < 16; ++k) {
    int t = k * 64 + l;
    float4 fa = make_float4(0.0f, 0.0f, 0.0f, 0.0f);
    float vx = 0.0f, lx = -1.0f;
    if (t < NTOP) {
      fa = *(const float4*)(src + t * 8);
      float2 fb = *(const float2*)(src + t * 8 + 4);
      vx = fb.x; lx = fb.y;
    }
    b0a[t] = fa.x; b1a[t] = fa.y; b2a[t] = fa.z; b3a[t] = fa.w;
    va_s[t] = vx; la_s[t] = (int)lx;
    rlab[k] = (int)lx;
    if (vx > 0.0f) amask |= (1u << k);
  }
  __syncthreads();

  const float scf = scalef[img];
  for (int i = 0; i < NDET; ++i) {
    // first alive in sorted order: lowest k with any alive lane, then lowest lane
    int j = -1;
    for (int k = 0; k < 16; ++k) {
      unsigned long long bal = __ballot((amask >> k) & 1u);
      if (bal != 0ull) { j = k * 64 + (__ffsll(bal) - 1); break; }
    }
    float* orow = out + ((size_t)img * NDET + i) * 6;
    if (j < 0) {
      if (l == 0) {
        orow[0] = 0.0f; orow[1] = 0.0f; orow[2] = 0.0f;
        orow[3] = 0.0f; orow[4] = 0.0f; orow[5] = -1.0f;
      }
      continue;
    }

    // broadcast reads (same address on all lanes -> conflict-free)
    float b0 = b0a[j], b1 = b1a[j], b2 = b2a[j], b3 = b3a[j];
    int lj = la_s[j];
    if (l == 0) {
      orow[0] = b0 / scf; orow[1] = b1 / scf;
      orow[2] = b2 / scf; orow[3] = b3 / scf;
      orow[4] = va_s[j];
      orow[5] = (float)lj;
    }
    float off = (float)lj * 4096.0f;
    float a0 = b0 + off, a1 = b1 + off, a2 = b2 + off, a3 = b3 + off;
    float areaA = (a2 - a0) * (a3 - a1);
    #pragma unroll
    for (int k = 0; k < 16; ++k) {
      if (!((amask >> k) & 1u)) continue;
      if (rlab[k] != lj) continue;              // cross-class IoU exactly 0 in ref
      int t = k * 64 + l;                       // bank = l%32: 2-way, conflict-free
      float o0 = b0a[t] + off, o1 = b1a[t] + off;
      float o2 = b2a[t] + off, o3 = b3a[t] + off;
      float ltx = fmaxf(a0, o0);
      float lty = fmaxf(a1, o1);
      float rbx = fminf(a2, o2);
      float rby = fminf(a3, o3);
      float wx = fmaxf(rbx - ltx, 0.0f);
      float wy = fmaxf(rby - lty, 0.0f);
      float inter = wx * wy;
      float a2r = (o2 - o0) * (o3 - o1);
      float denom = areaA + a2r - inter + 1e-7f;
      float iou = inter / denom;
      if (iou > 0.45f) amask &= ~(1u << k);     // includes t==j (ref self-suppression quirk)
    }
  }
}

// ---------------- launcher ----------------
extern "C" void kernel_launch(void* const* d_in, const int* in_sizes, int n_in,
                              void* d_out, int out_size, void* d_ws, size_t ws_size,
                              hipStream_t stream) {
  const float* p0 = (const float*)d_in[0];
  const float* p1 = (const float*)d_in[1];
  const float* p2 = (const float*)d_in[2];
  const float* anchors = (const float*)d_in[3];
  const float* scalef  = (const float*)d_in[4];
  float* out = (float*)d_out;

  char* w = (char*)d_ws;
  // layout (bytes): ghist 262144 | cnt 64 | tbin 64 | wcnt 64 | cand 524288 |
  //                 maxbin 806400 | worklist 262144 | boxes8 512000  (~2.26 MB)
  unsigned int* ghist = (unsigned int*)(w);
  int* cnt  = (int*)(w + 262144);
  int* tbin = (int*)(w + 262208);
  int* wcnt = (int*)(w + 262272);
  unsigned long long* cand = (unsigned long long*)(w + 262336);
  unsigned short* maxbin = (unsigned short*)(w + 262336 + 524288);       // 786624
  unsigned int* worklist = (unsigned int*)(w + 786624 + 806400);         // 1593024
  float* boxes8 = (float*)(w + 1593024 + 262144);                        // 1855168 (16B aligned)

  hipMemsetAsync(ghist, 0, 262144 + 192, stream);   // hist + cnt + tbin + wcnt

  k_passA<<<dim3(NIMG * TILES), dim3(256), 0, stream>>>(p0, p1, p2, ghist, maxbin);
  k_thresh<<<dim3(NIMG), dim3(256), 0, stream>>>(ghist, tbin);
  k_worklist<<<dim3((NIMG * NBOX + 255) / 256), dim3(256), 0, stream>>>(maxbin, tbin, worklist, wcnt);
  k_emit<<<dim3(256), dim3(256), 0, stream>>>(p0, p1, p2, worklist, wcnt, tbin, cand, cnt);
  k_sort<<<dim3(NIMG), dim3(256), 0, stream>>>(p0, p1, p2, anchors, cand, cnt, boxes8);
  k_nms<<<dim3(NIMG), dim3(64), 0, stream>>>(boxes8, scalef, out);
}

// Round 9
// 371.217 us; speedup vs baseline: 1.2215x; 1.2215x over previous
//
#include <hip/hip_runtime.h>
#include <cstdint>
#include <cstddef>

#pragma clang fp contract(off)

constexpr int NIMG  = 16;
constexpr int NB0   = 19200;   // 80*80*3
constexpr int NB1   = 4800;    // 40*40*3
constexpr int NB2   = 1200;    // 20*20*3
constexpr int NBOX  = 25200;
constexpr int NCLS  = 80;
constexpr int NCH   = 85;
constexpr int NBINS = 4096;
constexpr int CAP   = 4096;
constexpr int NTOP  = 1000;
constexpr int NDET  = 100;
constexpr int WLCAP = 65536;   // worklist capacity (<= NIMG*CAP)
constexpr float IMGSZ = 640.0f;
constexpr float BIN_SCALE = 4096.0f / 0.75f;

constexpr int CHUNK   = 32;            // boxes per LDS chunk (38 KB total LDS -> 4 blocks/CU)
constexpr int CHUNK_F = CHUNK * NCH;   // 2720 floats
constexpr int TILE    = 512;           // boxes per block (16 chunks)
constexpr int TILES   = (NBOX + TILE - 1) / TILE;   // 50

constexpr int IOU_RPB = 40;            // rows per k_iou block (25 blocks/img)

// ---------------- XLA-CPU-matching transcendentals (verified absmax=0) ----------------
__device__ __forceinline__ float xla_expf(float x) {
  const float kLog2e = 1.44269504088896341f;
  const float kC1 = 0.693359375f;
  const float kC2 = -2.12194440e-4f;
  const float cp0 = 1.9875691500e-4f;
  const float cp1 = 1.3981999507e-3f;
  const float cp2 = 8.3334519073e-3f;
  const float cp3 = 4.1665795894e-2f;
  const float cp4 = 1.6666665459e-1f;
  const float cp5 = 5.0000001201e-1f;
  float xc = fminf(x, 88.3762626647950f);
  xc = fmaxf(xc, -88.3762626647949f);
  float fx = floorf(fmaf(xc, kLog2e, 0.5f));
  float xr = fmaf(fx, -kC1, xc);
  xr = fmaf(fx, -kC2, xr);
  float z = xr * xr;
  float y = fmaf(cp0, xr, cp1);
  y = fmaf(y, xr, cp2);
  y = fmaf(y, xr, cp3);
  y = fmaf(y, xr, cp4);
  y = fmaf(y, xr, cp5);
  y = fmaf(y, z, xr);
  y = y + 1.0f;
  int n = (int)fx;
  float two_n = __int_as_float((n + 127) << 23);
  float r = y * two_n;
  return fmaxf(r, xc);
}

__device__ __forceinline__ float ref_sigmoid(float x) {
  return 1.0f / (1.0f + xla_expf(-x));
}

// ---------------- geometry helpers ----------------
__device__ __forceinline__ const float* locate(int img, int box,
    const float* __restrict__ p0, const float* __restrict__ p1, const float* __restrict__ p2,
    int& lvl, int& gx, int& gy, int& anc, float& stride) {
  const float* base; int r, W;
  if (box < NB0)            { lvl = 0; r = box;             W = 80; base = p0 + (size_t)img * NB0 * NCH; stride = 8.0f;  }
  else if (box < NB0 + NB1) { lvl = 1; r = box - NB0;       W = 40; base = p1 + (size_t)img * NB1 * NCH; stride = 16.0f; }
  else                      { lvl = 2; r = box - NB0 - NB1; W = 20; base = p2 + (size_t)img * NB2 * NCH; stride = 32.0f; }
  anc = r % 3;
  int cell = r / 3;
  gx = cell % W;
  gy = cell / W;
  return base + (size_t)r * NCH;
}

__device__ __forceinline__ float clip640(float v) {
  return fminf(fmaxf(v, 0.0f), IMGSZ);
}

// chunk (32 aligned boxes) never straddles a level boundary: 19200, 24000 are multiples of 32
__device__ __forceinline__ const float* chunk_ptr(int img, int first_box,
    const float* __restrict__ p0, const float* __restrict__ p1, const float* __restrict__ p2) {
  const float* base; int r;
  if (first_box < NB0)            { base = p0 + (size_t)img * NB0 * NCH; r = first_box; }
  else if (first_box < NB0 + NB1) { base = p1 + (size_t)img * NB1 * NCH; r = first_box - NB0; }
  else                            { base = p2 + (size_t)img * NB2 * NCH; r = first_box - NB0 - NB1; }
  return base + (size_t)r * NCH;
}

// ---------------- pass A: stream input once, histogram + per-box maxbin ----------------
__global__ __launch_bounds__(256) void k_passA(const float* __restrict__ p0,
    const float* __restrict__ p1, const float* __restrict__ p2,
    unsigned int* __restrict__ ghist, unsigned short* __restrict__ maxbin) {
  __shared__ __align__(16) float buf[2][CHUNK_F];   // 21.76 KB
  __shared__ unsigned int hist[NBINS];              // 16 KB
  const int tid = threadIdx.x;
  const int img  = blockIdx.x / TILES;
  const int tile = blockIdx.x % TILES;
  const int tbase = tile * TILE;
  const int nbox_tile = min(TILE, NBOX - tbase);
  const int nch = (nbox_tile + CHUNK - 1) / CHUNK;

  for (int i = tid; i < NBINS; i += 256) hist[i] = 0u;

  float4 regs[3];
  // prologue: load chunk 0 into buf[0]
  {
    int nb0c = min(CHUNK, nbox_tile);
    const float* cp = chunk_ptr(img, tbase, p0, p1, p2);
    int nv = (nb0c * NCH) / 4;   // <= 680
    const float4* cp4 = (const float4*)cp;
    float4* b4 = (float4*)&buf[0][0];
    #pragma unroll
    for (int k = 0; k < 3; ++k) { int i = tid + k * 256; if (i < nv) regs[k] = cp4[i]; }
    #pragma unroll
    for (int k = 0; k < 3; ++k) { int i = tid + k * 256; if (i < nv) b4[i] = regs[k]; }
  }
  __syncthreads();

  for (int c = 0; c < nch; ++c) {
    int nvN = 0;
    if (c + 1 < nch) {
      int fb = tbase + (c + 1) * CHUNK;
      int nbN = min(CHUNK, NBOX - fb);
      const float* cp = chunk_ptr(img, fb, p0, p1, p2);
      nvN = (nbN * NCH) / 4;
      const float4* cp4 = (const float4*)cp;
      #pragma unroll
      for (int k = 0; k < 3; ++k) { int i = tid + k * 256; if (i < nvN) regs[k] = cp4[i]; }
    }
    {
      int nb = min(CHUNK, nbox_tile - c * CHUNK);
      int b = tid >> 3, part = tid & 7;
      if (b < nb) {
        const float* row = &buf[c & 1][b * NCH];
        float obj = ref_sigmoid(row[4]);
        int mb = 0;
        if (obj > 0.25f) {
          float rr = 0.25f / obj;
          float tcons = __logf(rr / (1.0f - rr)) - 0.01f;   // conservative pre-filter
          #pragma unroll
          for (int cc = 0; cc < 10; ++cc) {
            float x = row[5 + part + 8 * cc];
            if (x > tcons) {
              float s = obj * ref_sigmoid(x);               // exact path
              if (s > 0.25f) {
                int bin = (int)((s - 0.25f) * BIN_SCALE);
                bin = min(bin, NBINS - 1);
                atomicAdd(&hist[bin], 1u);
                mb = max(mb, bin + 1);                      // stored = maxbin+1, 0 = none
              }
            }
          }
        }
        mb = max(mb, __shfl_xor(mb, 1, 8));
        mb = max(mb, __shfl_xor(mb, 2, 8));
        mb = max(mb, __shfl_xor(mb, 4, 8));
        if (part == 0)
          maxbin[(size_t)img * NBOX + tbase + c * CHUNK + b] = (unsigned short)mb;
      }
    }
    if (c + 1 < nch) {
      float4* b4 = (float4*)&buf[(c + 1) & 1][0];
      #pragma unroll
      for (int k = 0; k < 3; ++k) { int i = tid + k * 256; if (i < nvN) b4[i] = regs[k]; }
    }
    __syncthreads();
  }

  for (int i = tid; i < NBINS; i += 256) {
    unsigned int v = hist[i];
    if (v) atomicAdd(&ghist[img * NBINS + i], v);
  }
}

// ---------------- per-image threshold bin (parallel scan, 16 blocks) ----------------
__global__ __launch_bounds__(256) void k_thresh(const unsigned int* __restrict__ ghist,
                                                int* __restrict__ tbin) {
  __shared__ unsigned int h[NBINS];
  __shared__ unsigned int psum[256];
  const int tid = threadIdx.x;
  const int img = blockIdx.x;

  for (int i = tid; i < NBINS; i += 256) h[i] = ghist[img * NBINS + i];
  __syncthreads();
  unsigned int ps = 0;
  for (int k = 0; k < 16; ++k) ps += h[tid * 16 + k];
  psum[tid] = ps;
  __syncthreads();
  if (tid == 0) {
    long long cum = 0;
    int tb = 0;
    bool found = false;
    for (int g = 255; g >= 0 && !found; --g) {
      if (cum + (long long)psum[g] >= NTOP) {
        for (int b = g * 16 + 15; b >= g * 16; --b) {
          cum += h[b];
          if (cum >= NTOP) { tb = b; found = true; break; }
        }
      } else {
        cum += psum[g];
      }
    }
    if (!found) tb = 0;
    while (cum > CAP && tb < NBINS - 1) { cum -= h[tb]; ++tb; }
    tbin[img] = tb;
  }
}

// ---------------- worklist: compact passing rows (dense, coalesced) ----------------
__global__ __launch_bounds__(256) void k_worklist(const unsigned short* __restrict__ maxbin,
    const int* __restrict__ tbin, unsigned int* __restrict__ worklist,
    int* __restrict__ wcnt) {
  __shared__ int lcnt;
  __shared__ int lbase;
  const int tid = threadIdx.x;
  if (tid == 0) lcnt = 0;
  __syncthreads();
  int idx = blockIdx.x * 256 + tid;
  bool pass = false;
  int my = 0;
  int img = 0, box = 0;
  if (idx < NIMG * NBOX) {
    img = idx / NBOX;
    box = idx - img * NBOX;
    int mb = (int)maxbin[idx];
    if (mb > tbin[img]) {            // mb = maxbin+1 > tb  <=>  maxbin >= tb
      pass = true;
      my = atomicAdd(&lcnt, 1);
    }
  }
  __syncthreads();
  if (tid == 0 && lcnt > 0) lbase = atomicAdd(wcnt, lcnt);
  __syncthreads();
  if (pass) {
    int pos = lbase + my;
    if (pos < WLCAP) worklist[pos] = ((unsigned int)img << 16) | (unsigned int)box;
  }
}

// ---------------- emit: one dense row per thread, exact keys ----------------
__global__ __launch_bounds__(256) void k_emit(const float* __restrict__ p0,
    const float* __restrict__ p1, const float* __restrict__ p2,
    const unsigned int* __restrict__ worklist, const int* __restrict__ wcnt,
    const int* __restrict__ tbin, unsigned long long* __restrict__ cand,
    int* __restrict__ cnt) {
  int n = *wcnt;
  if (n > WLCAP) n = WLCAP;
  const int nthreads = gridDim.x * 256;
  for (int i = blockIdx.x * 256 + threadIdx.x; i < n; i += nthreads) {
    unsigned int e = worklist[i];
    int img = (int)(e >> 16);
    int box = (int)(e & 0xFFFFu);
    int lvl, gx, gy, anc; float stride;
    const float* ptr = locate(img, box, p0, p1, p2, lvl, gx, gy, anc, stride);
    float obj = ref_sigmoid(ptr[4]);
    if (obj <= 0.25f) continue;
    int tb = tbin[img];
    float rr = 0.25f / obj;
    float tcons = __logf(rr / (1.0f - rr)) - 0.01f;
    #pragma unroll 8
    for (int c = 0; c < NCLS; ++c) {
      float x = ptr[5 + c];
      if (x <= tcons) continue;
      float s = obj * ref_sigmoid(x);
      if (s > 0.25f) {
        int bin = (int)((s - 0.25f) * BIN_SCALE);
        bin = min(bin, NBINS - 1);
        if (bin >= tb) {
          int pos = atomicAdd(&cnt[img], 1);
          if (pos < CAP) {
            unsigned int fi = (unsigned int)(box * NCLS + c);
            unsigned long long key =
                ((unsigned long long)__float_as_uint(s) << 32) |
                (unsigned long long)(0xFFFFFFFFu - fi);
            cand[(size_t)img * CAP + pos] = key;
          }
        }
      }
    }
  }
}

// ---------------- sort + decode top-1000 into boxes8 (one block per image) ----------------
// swizzled LDS index: pad every 16 u64 keys to break the i/i+16 bank aliasing
#define SIDX(i) ((i) + ((i) >> 4))

__global__ __launch_bounds__(256) void k_sort(const float* __restrict__ p0,
    const float* __restrict__ p1, const float* __restrict__ p2,
    const float* __restrict__ anchors, const unsigned long long* __restrict__ cand,
    const int* __restrict__ cnt_arr, float* __restrict__ boxes8) {
  __shared__ unsigned long long keys[CAP + CAP / 16];   // 34.8 KB (swizzled)
  __shared__ int n2_sh, cnt_sh;
  const int tid = threadIdx.x;
  const int img = blockIdx.x;

  if (tid == 0) {
    int c = cnt_arr[img];
    c = max(0, min(c, CAP));
    int n2 = 1024;
    while (n2 < c) n2 <<= 1;
    cnt_sh = c; n2_sh = n2;
  }
  __syncthreads();
  const int cnt = cnt_sh;
  const int n2  = n2_sh;

  const unsigned long long* c = cand + (size_t)img * CAP;
  for (int i = tid; i < n2; i += 256) keys[SIDX(i)] = (i < cnt) ? c[i] : 0ull;
  __syncthreads();

  for (int kk = 2; kk <= n2; kk <<= 1) {
    for (int j = kk >> 1; j > 0; j >>= 1) {
      for (int i = tid; i < n2; i += 256) {
        int l = i ^ j;
        if (l > i) {
          unsigned long long a = keys[SIDX(i)], b = keys[SIDX(l)];
          bool up = ((i & kk) == 0);
          bool sw = up ? (a < b) : (a > b);
          if (sw) { keys[SIDX(i)] = b; keys[SIDX(l)] = a; }
        }
      }
      __syncthreads();
    }
  }

  // decode top-1000 -> boxes8[img][1000][8] = {b0,b1,b2,b3,val,label,0,0}
  float* dst = boxes8 + (size_t)img * NTOP * 8;
  for (int i = tid; i < NTOP; i += 256) {
    unsigned long long key = keys[SIDX(i)];
    unsigned int v = (unsigned int)(key >> 32);
    float4 fa, fb;
    if (v) {
      unsigned int idx = 0xFFFFFFFFu - (unsigned int)(key & 0xFFFFFFFFu);
      int box = (int)(idx / NCLS);
      int l   = (int)(idx % NCLS);
      int lvl, gx, gy, anc; float stride;
      const float* ptr = locate(img, box, p0, p1, p2, lvl, gx, gy, anc, stride);
      float sx = ref_sigmoid(ptr[0]);
      float sy = ref_sigmoid(ptr[1]);
      float sw = ref_sigmoid(ptr[2]);
      float sh = ref_sigmoid(ptr[3]);
      float aw = anchors[(lvl * 3 + anc) * 2 + 0];
      float ah = anchors[(lvl * 3 + anc) * 2 + 1];
      float cx = (2.0f * sx - 0.5f + (float)gx) * stride;
      float cy = (2.0f * sy - 0.5f + (float)gy) * stride;
      float ww = (4.0f * (sw * sw)) * aw;
      float hh = (4.0f * (sh * sh)) * ah;
      fa.x = clip640(cx - ww * 0.5f);
      fa.y = clip640(cy - hh * 0.5f);
      fa.z = clip640(cx + ww * 0.5f);
      fa.w = clip640(cy + hh * 0.5f);
      fb.x = __uint_as_float(v);
      fb.y = (float)l;
      fb.z = 0.0f; fb.w = 0.0f;
    } else {
      fa.x = fa.y = fa.z = fa.w = 0.0f;
      fb.x = 0.0f; fb.y = -1.0f; fb.z = 0.0f; fb.w = 0.0f;
    }
    *(float4*)(dst + i * 8)     = fa;
    *(float4*)(dst + i * 8 + 4) = fb;
  }
}

// ---------------- IoU suppression matrix: bit[r][t] = iou(obx[r],obx[t]) > 0.45 ----------
// obx = box + label*4096 exactly as the ref (cross-class inter is exactly 0).
// One wave computes 64 cols of one row -> __ballot -> u64 word. Fully parallel.
__global__ __launch_bounds__(256) void k_iou(const float* __restrict__ boxes8,
                                             unsigned int* __restrict__ mat) {
  __shared__ float obx[NTOP * 5];   // stride 5 -> lane col-reads are 2-way (free)
  const int img = blockIdx.x / (NTOP / IOU_RPB);
  const int rg  = blockIdx.x % (NTOP / IOU_RPB);
  const float* src = boxes8 + (size_t)img * NTOP * 8;

  for (int t = threadIdx.x; t < NTOP; t += 256) {
    float4 fa = *(const float4*)(src + t * 8);
    float lab = src[t * 8 + 5];
    float off = lab * 4096.0f;          // exact fp32 (ref: lab*MAX_SIZE)
    obx[t * 5 + 0] = fa.x + off;
    obx[t * 5 + 1] = fa.y + off;
    obx[t * 5 + 2] = fa.z + off;
    obx[t * 5 + 3] = fa.w + off;
  }
  __syncthreads();

  const int wave = threadIdx.x >> 6;
  const int lane = threadIdx.x & 63;
  for (int task = wave; task < IOU_RPB * 16; task += 4) {
    int r = rg * IOU_RPB + (task >> 4);
    int w = task & 15;
    float a0 = obx[r * 5 + 0], a1 = obx[r * 5 + 1];   // broadcast reads
    float a2 = obx[r * 5 + 2], a3 = obx[r * 5 + 3];
    float areaA = (a2 - a0) * (a3 - a1);
    int col = w * 64 + lane;
    bool bit = false;
    if (col < NTOP) {
      float o0 = obx[col * 5 + 0], o1 = obx[col * 5 + 1];
      float o2 = obx[col * 5 + 2], o3 = obx[col * 5 + 3];
      float ltx = fmaxf(a0, o0);
      float lty = fmaxf(a1, o1);
      float rbx = fminf(a2, o2);
      float rby = fminf(a3, o3);
      float wx = fmaxf(rbx - ltx, 0.0f);
      float wy = fmaxf(rby - lty, 0.0f);
      float inter = wx * wy;
      float a2r = (o2 - o0) * (o3 - o1);
      float denom = areaA + a2r - inter + 1e-7f;      // ((a1+a2)-inter)+1e-7, contract off
      bit = (inter / denom) > 0.45f;
    }
    unsigned long long m = __ballot(bit);
    if (lane == 0)
      *(unsigned long long*)(mat + ((size_t)img * NTOP + r) * 32 + w * 2) = m;
  }
}

// ---------------- NMS greedy: O(1) serial work per pick ----------
// Matrix staged in LDS (125 KB); alive mask = 1 register/lane (lane l owns bits
// [32l,32l+32)). Per pick: ballot -> ffs -> shfl -> ffs (= min index = ref's
// sorted-order argmax with exact tie-break), then one conflict-free LDS row AND.
__global__ __launch_bounds__(64) void k_nms(const unsigned int* __restrict__ mat,
    const float* __restrict__ boxes8, const float* __restrict__ scalef,
    float* __restrict__ out) {
  __shared__ uint4 mat_lds4[NTOP * 8];   // 1000 rows x 32 u32 = 128000 B
  unsigned int* mat_lds = (unsigned int*)mat_lds4;
  const int lane = threadIdx.x;
  const int img = blockIdx.x;
  const float* src = boxes8 + (size_t)img * NTOP * 8;

  const uint4* msrc = (const uint4*)(mat + (size_t)img * NTOP * 32);
  for (int i = lane; i < NTOP * 8; i += 64) mat_lds4[i] = msrc[i];

  // alive init: lane l (<32) owns u32 word for bits t in [32l, 32l+32)
  unsigned int aw = 0u;
  for (int w = 0; w < 16; ++w) {
    int t = w * 64 + lane;
    float va = (t < NTOP) ? src[t * 8 + 4] : 0.0f;
    unsigned long long b = __ballot(va > 0.0f);
    if (lane == 2 * w)     aw = (unsigned int)b;
    if (lane == 2 * w + 1) aw = (unsigned int)(b >> 32);
  }
  if (lane >= 32) aw = 0u;
  __syncthreads();

  int pj0 = -1, pj1 = -1;   // pick i stored in lane (i&63): pj0 for i<64, pj1 else
  for (int i = 0; i < NDET; ++i) {
    unsigned long long bal = __ballot(aw != 0u);
    int j = -1;
    if (bal != 0ull) {
      int L = __ffsll(bal) - 1;
      unsigned int wL = (unsigned int)__shfl((int)aw, L);
      j = L * 32 + (__ffs(wL) - 1);
    }
    if (lane == (i & 63)) { if (i < 64) pj0 = j; else pj1 = j; }
    if (j >= 0 && lane < 32) aw &= ~mat_lds[j * 32 + lane];   // bank l: conflict-free
  }

  // parallel emit (off the greedy critical path)
  const float scf = scalef[img];
  #pragma unroll
  for (int rep = 0; rep < 2; ++rep) {
    int i = rep * 64 + lane;
    if (i >= NDET) break;
    int j = (rep == 0) ? pj0 : pj1;
    float* orow = out + ((size_t)img * NDET + i) * 6;
    if (j < 0) {
      orow[0] = 0.0f; orow[1] = 0.0f; orow[2] = 0.0f;
      orow[3] = 0.0f; orow[4] = 0.0f; orow[5] = -1.0f;
    } else {
      float4 fa = *(const float4*)(src + j * 8);
      float va = src[j * 8 + 4];
      float lb = src[j * 8 + 5];
      orow[0] = fa.x / scf; orow[1] = fa.y / scf;
      orow[2] = fa.z / scf; orow[3] = fa.w / scf;
      orow[4] = va;
      orow[5] = lb;
    }
  }
}

// ---------------- launcher ----------------
extern "C" void kernel_launch(void* const* d_in, const int* in_sizes, int n_in,
                              void* d_out, int out_size, void* d_ws, size_t ws_size,
                              hipStream_t stream) {
  const float* p0 = (const float*)d_in[0];
  const float* p1 = (const float*)d_in[1];
  const float* p2 = (const float*)d_in[2];
  const float* anchors = (const float*)d_in[3];
  const float* scalef  = (const float*)d_in[4];
  float* out = (float*)d_out;

  char* w = (char*)d_ws;
  // layout (bytes): ghist 262144 | cnt 64 | tbin 64 | wcnt 64 | cand 524288 |
  //   maxbin 806400 | worklist 262144 | boxes8 512000 | mat 2048000  (~4.42 MB)
  unsigned int* ghist = (unsigned int*)(w);
  int* cnt  = (int*)(w + 262144);
  int* tbin = (int*)(w + 262208);
  int* wcnt = (int*)(w + 262272);
  unsigned long long* cand = (unsigned long long*)(w + 262336);
  unsigned short* maxbin = (unsigned short*)(w + 262336 + 524288);       // 786624
  unsigned int* worklist = (unsigned int*)(w + 786624 + 806400);         // 1593024
  float* boxes8 = (float*)(w + 1593024 + 262144);                        // 1855168
  unsigned int* mat = (unsigned int*)(w + 1855168 + 512000);             // 2367168

  hipMemsetAsync(ghist, 0, 262144 + 192, stream);   // hist + cnt + tbin + wcnt

  k_passA<<<dim3(NIMG * TILES), dim3(256), 0, stream>>>(p0, p1, p2, ghist, maxbin);
  k_thresh<<<dim3(NIMG), dim3(256), 0, stream>>>(ghist, tbin);
  k_worklist<<<dim3((NIMG * NBOX + 255) / 256), dim3(256), 0, stream>>>(maxbin, tbin, worklist, wcnt);
  k_emit<<<dim3(256), dim3(256), 0, stream>>>(p0, p1, p2, worklist, wcnt, tbin, cand, cnt);
  k_sort<<<dim3(NIMG), dim3(256), 0, stream>>>(p0, p1, p2, anchors, cand, cnt, boxes8);
  k_iou<<<dim3(NIMG * (NTOP / IOU_RPB)), dim3(256), 0, stream>>>(boxes8, mat);
  k_nms<<<dim3(NIMG), dim3(64), 0, stream>>>(mat, boxes8, scalef, out);
}

// Round 10
// 291.853 us; speedup vs baseline: 1.5537x; 1.2719x over previous
//
#include <hip/hip_runtime.h>
#include <cstdint>
#include <cstddef>

#pragma clang fp contract(off)

constexpr int NIMG  = 16;
constexpr int NB0   = 19200;   // 80*80*3
constexpr int NB1   = 4800;    // 40*40*3
constexpr int NB2   = 1200;    // 20*20*3
constexpr int NBOX  = 25200;
constexpr int NCLS  = 80;
constexpr int NCH   = 85;
constexpr int NBINS = 4096;
constexpr int CAP   = 4096;
constexpr int NTOP  = 1000;
constexpr int NDET  = 100;
constexpr int WLCAP = 65536;   // worklist capacity (<= NIMG*CAP)
constexpr float IMGSZ = 640.0f;
constexpr float BIN_SCALE = 4096.0f / 0.75f;

constexpr int CHUNK   = 32;            // boxes per LDS chunk (38 KB total LDS -> 4 blocks/CU)
constexpr int CHUNK_F = CHUNK * NCH;   // 2720 floats
constexpr int TILE    = 512;           // boxes per block (16 chunks)
constexpr int TILES   = (NBOX + TILE - 1) / TILE;   // 50

constexpr int IOU_RPB = 40;            // rows per k_iou block (25 blocks/img)

// ---------------- XLA-CPU-matching transcendentals (verified absmax=0) ----------------
__device__ __forceinline__ float xla_expf(float x) {
  const float kLog2e = 1.44269504088896341f;
  const float kC1 = 0.693359375f;
  const float kC2 = -2.12194440e-4f;
  const float cp0 = 1.9875691500e-4f;
  const float cp1 = 1.3981999507e-3f;
  const float cp2 = 8.3334519073e-3f;
  const float cp3 = 4.1665795894e-2f;
  const float cp4 = 1.6666665459e-1f;
  const float cp5 = 5.0000001201e-1f;
  float xc = fminf(x, 88.3762626647950f);
  xc = fmaxf(xc, -88.3762626647949f);
  float fx = floorf(fmaf(xc, kLog2e, 0.5f));
  float xr = fmaf(fx, -kC1, xc);
  xr = fmaf(fx, -kC2, xr);
  float z = xr * xr;
  float y = fmaf(cp0, xr, cp1);
  y = fmaf(y, xr, cp2);
  y = fmaf(y, xr, cp3);
  y = fmaf(y, xr, cp4);
  y = fmaf(y, xr, cp5);
  y = fmaf(y, z, xr);
  y = y + 1.0f;
  int n = (int)fx;
  float two_n = __int_as_float((n + 127) << 23);
  float r = y * two_n;
  return fmaxf(r, xc);
}

__device__ __forceinline__ float ref_sigmoid(float x) {
  return 1.0f / (1.0f + xla_expf(-x));
}

// ---------------- geometry helpers ----------------
__device__ __forceinline__ const float* locate(int img, int box,
    const float* __restrict__ p0, const float* __restrict__ p1, const float* __restrict__ p2,
    int& lvl, int& gx, int& gy, int& anc, float& stride) {
  const float* base; int r, W;
  if (box < NB0)            { lvl = 0; r = box;             W = 80; base = p0 + (size_t)img * NB0 * NCH; stride = 8.0f;  }
  else if (box < NB0 + NB1) { lvl = 1; r = box - NB0;       W = 40; base = p1 + (size_t)img * NB1 * NCH; stride = 16.0f; }
  else                      { lvl = 2; r = box - NB0 - NB1; W = 20; base = p2 + (size_t)img * NB2 * NCH; stride = 32.0f; }
  anc = r % 3;
  int cell = r / 3;
  gx = cell % W;
  gy = cell / W;
  return base + (size_t)r * NCH;
}

__device__ __forceinline__ float clip640(float v) {
  return fminf(fmaxf(v, 0.0f), IMGSZ);
}

// chunk (32 aligned boxes) never straddles a level boundary: 19200, 24000 are multiples of 32
__device__ __forceinline__ const float* chunk_ptr(int img, int first_box,
    const float* __restrict__ p0, const float* __restrict__ p1, const float* __restrict__ p2) {
  const float* base; int r;
  if (first_box < NB0)            { base = p0 + (size_t)img * NB0 * NCH; r = first_box; }
  else if (first_box < NB0 + NB1) { base = p1 + (size_t)img * NB1 * NCH; r = first_box - NB0; }
  else                            { base = p2 + (size_t)img * NB2 * NCH; r = first_box - NB0 - NB1; }
  return base + (size_t)r * NCH;
}

// ---------------- pass A: stream input once, histogram + per-box maxbin ----------------
__global__ __launch_bounds__(256) void k_passA(const float* __restrict__ p0,
    const float* __restrict__ p1, const float* __restrict__ p2,
    unsigned int* __restrict__ ghist, unsigned short* __restrict__ maxbin) {
  __shared__ __align__(16) float buf[2][CHUNK_F];   // 21.76 KB
  __shared__ unsigned int hist[NBINS];              // 16 KB
  const int tid = threadIdx.x;
  const int img  = blockIdx.x / TILES;
  const int tile = blockIdx.x % TILES;
  const int tbase = tile * TILE;
  const int nbox_tile = min(TILE, NBOX - tbase);
  const int nch = (nbox_tile + CHUNK - 1) / CHUNK;

  for (int i = tid; i < NBINS; i += 256) hist[i] = 0u;

  float4 regs[3];
  // prologue: load chunk 0 into buf[0]
  {
    int nb0c = min(CHUNK, nbox_tile);
    const float* cp = chunk_ptr(img, tbase, p0, p1, p2);
    int nv = (nb0c * NCH) / 4;   // <= 680
    const float4* cp4 = (const float4*)cp;
    float4* b4 = (float4*)&buf[0][0];
    #pragma unroll
    for (int k = 0; k < 3; ++k) { int i = tid + k * 256; if (i < nv) regs[k] = cp4[i]; }
    #pragma unroll
    for (int k = 0; k < 3; ++k) { int i = tid + k * 256; if (i < nv) b4[i] = regs[k]; }
  }
  __syncthreads();

  for (int c = 0; c < nch; ++c) {
    int nvN = 0;
    if (c + 1 < nch) {
      int fb = tbase + (c + 1) * CHUNK;
      int nbN = min(CHUNK, NBOX - fb);
      const float* cp = chunk_ptr(img, fb, p0, p1, p2);
      nvN = (nbN * NCH) / 4;
      const float4* cp4 = (const float4*)cp;
      #pragma unroll
      for (int k = 0; k < 3; ++k) { int i = tid + k * 256; if (i < nvN) regs[k] = cp4[i]; }
    }
    {
      int nb = min(CHUNK, nbox_tile - c * CHUNK);
      int b = tid >> 3, part = tid & 7;
      if (b < nb) {
        const float* row = &buf[c & 1][b * NCH];
        float obj = ref_sigmoid(row[4]);
        int mb = 0;
        if (obj > 0.25f) {
          float rr = 0.25f / obj;
          float tcons = __logf(rr / (1.0f - rr)) - 0.01f;   // conservative pre-filter
          #pragma unroll
          for (int cc = 0; cc < 10; ++cc) {
            float x = row[5 + part + 8 * cc];
            if (x > tcons) {
              float s = obj * ref_sigmoid(x);               // exact path
              if (s > 0.25f) {
                int bin = (int)((s - 0.25f) * BIN_SCALE);
                bin = min(bin, NBINS - 1);
                atomicAdd(&hist[bin], 1u);
                mb = max(mb, bin + 1);                      // stored = maxbin+1, 0 = none
              }
            }
          }
        }
        mb = max(mb, __shfl_xor(mb, 1, 8));
        mb = max(mb, __shfl_xor(mb, 2, 8));
        mb = max(mb, __shfl_xor(mb, 4, 8));
        if (part == 0)
          maxbin[(size_t)img * NBOX + tbase + c * CHUNK + b] = (unsigned short)mb;
      }
    }
    if (c + 1 < nch) {
      float4* b4 = (float4*)&buf[(c + 1) & 1][0];
      #pragma unroll
      for (int k = 0; k < 3; ++k) { int i = tid + k * 256; if (i < nvN) b4[i] = regs[k]; }
    }
    __syncthreads();
  }

  for (int i = tid; i < NBINS; i += 256) {
    unsigned int v = hist[i];
    if (v) atomicAdd(&ghist[img * NBINS + i], v);
  }
}

// ---------------- per-image threshold bin (parallel scan, 16 blocks) ----------------
__global__ __launch_bounds__(256) void k_thresh(const unsigned int* __restrict__ ghist,
                                                int* __restrict__ tbin) {
  __shared__ unsigned int h[NBINS];
  __shared__ unsigned int psum[256];
  const int tid = threadIdx.x;
  const int img = blockIdx.x;

  for (int i = tid; i < NBINS; i += 256) h[i] = ghist[img * NBINS + i];
  __syncthreads();
  unsigned int ps = 0;
  for (int k = 0; k < 16; ++k) ps += h[tid * 16 + k];
  psum[tid] = ps;
  __syncthreads();
  if (tid == 0) {
    long long cum = 0;
    int tb = 0;
    bool found = false;
    for (int g = 255; g >= 0 && !found; --g) {
      if (cum + (long long)psum[g] >= NTOP) {
        for (int b = g * 16 + 15; b >= g * 16; --b) {
          cum += h[b];
          if (cum >= NTOP) { tb = b; found = true; break; }
        }
      } else {
        cum += psum[g];
      }
    }
    if (!found) tb = 0;
    while (cum > CAP && tb < NBINS - 1) { cum -= h[tb]; ++tb; }
    tbin[img] = tb;
  }
}

// ---------------- worklist: compact passing rows (dense, coalesced) ----------------
__global__ __launch_bounds__(256) void k_worklist(const unsigned short* __restrict__ maxbin,
    const int* __restrict__ tbin, unsigned int* __restrict__ worklist,
    int* __restrict__ wcnt) {
  __shared__ int lcnt;
  __shared__ int lbase;
  const int tid = threadIdx.x;
  if (tid == 0) lcnt = 0;
  __syncthreads();
  int idx = blockIdx.x * 256 + tid;
  bool pass = false;
  int my = 0;
  int img = 0, box = 0;
  if (idx < NIMG * NBOX) {
    img = idx / NBOX;
    box = idx - img * NBOX;
    int mb = (int)maxbin[idx];
    if (mb > tbin[img]) {            // mb = maxbin+1 > tb  <=>  maxbin >= tb
      pass = true;
      my = atomicAdd(&lcnt, 1);
    }
  }
  __syncthreads();
  if (tid == 0 && lcnt > 0) lbase = atomicAdd(wcnt, lcnt);
  __syncthreads();
  if (pass) {
    int pos = lbase + my;
    if (pos < WLCAP) worklist[pos] = ((unsigned int)img << 16) | (unsigned int)box;
  }
}

// ---------------- emit: wave-aggregated slot allocation (two-pass) ----------------
// Round-9 post-mortem: per-candidate atomicAdd(&cnt[img]) with return serializes
// ~2500 ops/address at the L2 (~120 cy each ~= 123 us). Pass 1 counts candidates
// per row; a wave-level img-grouped prefix sum issues ONE atomic per wave-group
// (~800 total); pass 2 recomputes and stores. Emission order changes but k_sort's
// strict total order on the 64-bit keys canonicalizes -> absmax unchanged.
__global__ __launch_bounds__(256) void k_emit(const float* __restrict__ p0,
    const float* __restrict__ p1, const float* __restrict__ p2,
    const unsigned int* __restrict__ worklist, const int* __restrict__ wcnt,
    const int* __restrict__ tbin, unsigned long long* __restrict__ cand,
    int* __restrict__ cnt) {
  int n = *wcnt;
  if (n > WLCAP) n = WLCAP;
  const int lane = threadIdx.x & 63;
  const int nthreads = gridDim.x * 256;
  for (int i0 = blockIdx.x * 256 + threadIdx.x; ; i0 += nthreads) {
    bool haverow = (i0 < n);
    if (__ballot(haverow) == 0ull) break;   // wave-uniform exit keeps lanes convergent

    int img = 0, box = 0, tb = 0, nc = 0;
    const float* ptr = nullptr;
    float obj = 0.0f, tcons = 0.0f;
    if (haverow) {
      unsigned int e = worklist[i0];
      img = (int)(e >> 16);
      box = (int)(e & 0xFFFFu);
      int lvl, gx, gy, anc; float stride;
      ptr = locate(img, box, p0, p1, p2, lvl, gx, gy, anc, stride);
      obj = ref_sigmoid(ptr[4]);
      if (obj > 0.25f) {
        tb = tbin[img];
        float rr = 0.25f / obj;
        tcons = __logf(rr / (1.0f - rr)) - 0.01f;
        // pass 1: count candidates for this row
        #pragma unroll 8
        for (int c = 0; c < NCLS; ++c) {
          float x = ptr[5 + c];
          if (x <= tcons) continue;
          float s = obj * ref_sigmoid(x);
          if (s > 0.25f) {
            int bin = (int)((s - 0.25f) * BIN_SCALE);
            bin = min(bin, NBINS - 1);
            if (bin >= tb) ++nc;
          }
        }
      }
    }

    // wave-aggregated base assignment, grouped by img (usually 1-2 groups/wave)
    int mybase = 0;
    unsigned long long active = __ballot(nc > 0);
    while (active) {
      int leader = __ffsll(active) - 1;
      int limg = __shfl(img, leader);
      bool mine = (nc > 0) && (img == limg);
      unsigned long long grp = __ballot(mine);
      int incl = mine ? nc : 0;
      #pragma unroll
      for (int d = 1; d < 64; d <<= 1) {
        int t = __shfl_up(incl, d);
        if (lane >= d) incl += t;
      }
      int hi = 63 - __clzll(grp);
      int total = __shfl(incl, hi);
      int base = 0;
      if (lane == leader) base = atomicAdd(&cnt[limg], total);
      base = __shfl(base, leader);
      if (mine) mybase = base + incl - nc;
      active &= ~grp;
    }

    // pass 2: recompute and store at assigned slots
    if (nc > 0) {
      int pos = mybase;
      #pragma unroll 8
      for (int c = 0; c < NCLS; ++c) {
        float x = ptr[5 + c];
        if (x <= tcons) continue;
        float s = obj * ref_sigmoid(x);
        if (s > 0.25f) {
          int bin = (int)((s - 0.25f) * BIN_SCALE);
          bin = min(bin, NBINS - 1);
          if (bin >= tb) {
            if (pos < CAP) {
              unsigned int fi = (unsigned int)(box * NCLS + c);
              unsigned long long key =
                  ((unsigned long long)__float_as_uint(s) << 32) |
                  (unsigned long long)(0xFFFFFFFFu - fi);
              cand[(size_t)img * CAP + pos] = key;
            }
            ++pos;
          }
        }
      }
    }
  }
}

// ---------------- sort + decode top-1000 into boxes8 (one block per image) ----------------
// swizzled LDS index: pad every 16 u64 keys to break the i/i+16 bank aliasing
#define SIDX(i) ((i) + ((i) >> 4))

__global__ __launch_bounds__(256) void k_sort(const float* __restrict__ p0,
    const float* __restrict__ p1, const float* __restrict__ p2,
    const float* __restrict__ anchors, const unsigned long long* __restrict__ cand,
    const int* __restrict__ cnt_arr, float* __restrict__ boxes8) {
  __shared__ unsigned long long keys[CAP + CAP / 16];   // 34.8 KB (swizzled)
  __shared__ int n2_sh, cnt_sh;
  const int tid = threadIdx.x;
  const int img = blockIdx.x;

  if (tid == 0) {
    int c = cnt_arr[img];
    c = max(0, min(c, CAP));
    int n2 = 1024;
    while (n2 < c) n2 <<= 1;
    cnt_sh = c; n2_sh = n2;
  }
  __syncthreads();
  const int cnt = cnt_sh;
  const int n2  = n2_sh;

  const unsigned long long* c = cand + (size_t)img * CAP;
  for (int i = tid; i < n2; i += 256) keys[SIDX(i)] = (i < cnt) ? c[i] : 0ull;
  __syncthreads();

  for (int kk = 2; kk <= n2; kk <<= 1) {
    for (int j = kk >> 1; j > 0; j >>= 1) {
      for (int i = tid; i < n2; i += 256) {
        int l = i ^ j;
        if (l > i) {
          unsigned long long a = keys[SIDX(i)], b = keys[SIDX(l)];
          bool up = ((i & kk) == 0);
          bool sw = up ? (a < b) : (a > b);
          if (sw) { keys[SIDX(i)] = b; keys[SIDX(l)] = a; }
        }
      }
      __syncthreads();
    }
  }

  // decode top-1000 -> boxes8[img][1000][8] = {b0,b1,b2,b3,val,label,0,0}
  float* dst = boxes8 + (size_t)img * NTOP * 8;
  for (int i = tid; i < NTOP; i += 256) {
    unsigned long long key = keys[SIDX(i)];
    unsigned int v = (unsigned int)(key >> 32);
    float4 fa, fb;
    if (v) {
      unsigned int idx = 0xFFFFFFFFu - (unsigned int)(key & 0xFFFFFFFFu);
      int box = (int)(idx / NCLS);
      int l   = (int)(idx % NCLS);
      int lvl, gx, gy, anc; float stride;
      const float* ptr = locate(img, box, p0, p1, p2, lvl, gx, gy, anc, stride);
      float sx = ref_sigmoid(ptr[0]);
      float sy = ref_sigmoid(ptr[1]);
      float sw = ref_sigmoid(ptr[2]);
      float sh = ref_sigmoid(ptr[3]);
      float aw = anchors[(lvl * 3 + anc) * 2 + 0];
      float ah = anchors[(lvl * 3 + anc) * 2 + 1];
      float cx = (2.0f * sx - 0.5f + (float)gx) * stride;
      float cy = (2.0f * sy - 0.5f + (float)gy) * stride;
      float ww = (4.0f * (sw * sw)) * aw;
      float hh = (4.0f * (sh * sh)) * ah;
      fa.x = clip640(cx - ww * 0.5f);
      fa.y = clip640(cy - hh * 0.5f);
      fa.z = clip640(cx + ww * 0.5f);
      fa.w = clip640(cy + hh * 0.5f);
      fb.x = __uint_as_float(v);
      fb.y = (float)l;
      fb.z = 0.0f; fb.w = 0.0f;
    } else {
      fa.x = fa.y = fa.z = fa.w = 0.0f;
      fb.x = 0.0f; fb.y = -1.0f; fb.z = 0.0f; fb.w = 0.0f;
    }
    *(float4*)(dst + i * 8)     = fa;
    *(float4*)(dst + i * 8 + 4) = fb;
  }
}

// ---------------- IoU suppression matrix: bit[r][t] = iou(obx[r],obx[t]) > 0.45 ----------
__global__ __launch_bounds__(256) void k_iou(const float* __restrict__ boxes8,
                                             unsigned int* __restrict__ mat) {
  __shared__ float obx[NTOP * 5];   // stride 5 -> lane col-reads are 2-way (free)
  const int img = blockIdx.x / (NTOP / IOU_RPB);
  const int rg  = blockIdx.x % (NTOP / IOU_RPB);
  const float* src = boxes8 + (size_t)img * NTOP * 8;

  for (int t = threadIdx.x; t < NTOP; t += 256) {
    float4 fa = *(const float4*)(src + t * 8);
    float lab = src[t * 8 + 5];
    float off = lab * 4096.0f;          // exact fp32 (ref: lab*MAX_SIZE)
    obx[t * 5 + 0] = fa.x + off;
    obx[t * 5 + 1] = fa.y + off;
    obx[t * 5 + 2] = fa.z + off;
    obx[t * 5 + 3] = fa.w + off;
  }
  __syncthreads();

  const int wave = threadIdx.x >> 6;
  const int lane = threadIdx.x & 63;
  for (int task = wave; task < IOU_RPB * 16; task += 4) {
    int r = rg * IOU_RPB + (task >> 4);
    int w = task & 15;
    float a0 = obx[r * 5 + 0], a1 = obx[r * 5 + 1];   // broadcast reads
    float a2 = obx[r * 5 + 2], a3 = obx[r * 5 + 3];
    float areaA = (a2 - a0) * (a3 - a1);
    int col = w * 64 + lane;
    bool bit = false;
    if (col < NTOP) {
      float o0 = obx[col * 5 + 0], o1 = obx[col * 5 + 1];
      float o2 = obx[col * 5 + 2], o3 = obx[col * 5 + 3];
      float ltx = fmaxf(a0, o0);
      float lty = fmaxf(a1, o1);
      float rbx = fminf(a2, o2);
      float rby = fminf(a3, o3);
      float wx = fmaxf(rbx - ltx, 0.0f);
      float wy = fmaxf(rby - lty, 0.0f);
      float inter = wx * wy;
      float a2r = (o2 - o0) * (o3 - o1);
      float denom = areaA + a2r - inter + 1e-7f;      // ((a1+a2)-inter)+1e-7, contract off
      bit = (inter / denom) > 0.45f;
    }
    unsigned long long m = __ballot(bit);
    if (lane == 0)
      *(unsigned long long*)(mat + ((size_t)img * NTOP + r) * 32 + w * 2) = m;
  }
}

// ---------------- NMS greedy: O(1) serial work per pick ----------
__global__ __launch_bounds__(64) void k_nms(const unsigned int* __restrict__ mat,
    const float* __restrict__ boxes8, const float* __restrict__ scalef,
    float* __restrict__ out) {
  __shared__ uint4 mat_lds4[NTOP * 8];   // 1000 rows x 32 u32 = 128000 B
  unsigned int* mat_lds = (unsigned int*)mat_lds4;
  const int lane = threadIdx.x;
  const int img = blockIdx.x;
  const float* src = boxes8 + (size_t)img * NTOP * 8;

  const uint4* msrc = (const uint4*)(mat + (size_t)img * NTOP * 32);
  for (int i = lane; i < NTOP * 8; i += 64) mat_lds4[i] = msrc[i];

  // alive init: lane l (<32) owns u32 word for bits t in [32l, 32l+32)
  unsigned int aw = 0u;
  for (int w = 0; w < 16; ++w) {
    int t = w * 64 + lane;
    float va = (t < NTOP) ? src[t * 8 + 4] : 0.0f;
    unsigned long long b = __ballot(va > 0.0f);
    if (lane == 2 * w)     aw = (unsigned int)b;
    if (lane == 2 * w + 1) aw = (unsigned int)(b >> 32);
  }
  if (lane >= 32) aw = 0u;
  __syncthreads();

  int pj0 = -1, pj1 = -1;   // pick i stored in lane (i&63): pj0 for i<64, pj1 else
  for (int i = 0; i < NDET; ++i) {
    unsigned long long bal = __ballot(aw != 0u);
    int j = -1;
    if (bal != 0ull) {
      int L = __ffsll(bal) - 1;
      unsigned int wL = (unsigned int)__shfl((int)aw, L);
      j = L * 32 + (__ffs(wL) - 1);
    }
    if (lane == (i & 63)) { if (i < 64) pj0 = j; else pj1 = j; }
    if (j >= 0 && lane < 32) aw &= ~mat_lds[j * 32 + lane];   // bank l: conflict-free
  }

  // parallel emit (off the greedy critical path)
  const float scf = scalef[img];
  #pragma unroll
  for (int rep = 0; rep < 2; ++rep) {
    int i = rep * 64 + lane;
    if (i >= NDET) break;
    int j = (rep == 0) ? pj0 : pj1;
    float* orow = out + ((size_t)img * NDET + i) * 6;
    if (j < 0) {
      orow[0] = 0.0f; orow[1] = 0.0f; orow[2] = 0.0f;
      orow[3] = 0.0f; orow[4] = 0.0f; orow[5] = -1.0f;
    } else {
      float4 fa = *(const float4*)(src + j * 8);
      float va = src[j * 8 + 4];
      float lb = src[j * 8 + 5];
      orow[0] = fa.x / scf; orow[1] = fa.y / scf;
      orow[2] = fa.z / scf; orow[3] = fa.w / scf;
      orow[4] = va;
      orow[5] = lb;
    }
  }
}

// ---------------- launcher ----------------
extern "C" void kernel_launch(void* const* d_in, const int* in_sizes, int n_in,
                              void* d_out, int out_size, void* d_ws, size_t ws_size,
                              hipStream_t stream) {
  const float* p0 = (const float*)d_in[0];
  const float* p1 = (const float*)d_in[1];
  const float* p2 = (const float*)d_in[2];
  const float* anchors = (const float*)d_in[3];
  const float* scalef  = (const float*)d_in[4];
  float* out = (float*)d_out;

  char* w = (char*)d_ws;
  // layout (bytes): ghist 262144 | cnt 64 | tbin 64 | wcnt 64 | cand 524288 |
  //   maxbin 806400 | worklist 262144 | boxes8 512000 | mat 2048000  (~4.42 MB)
  unsigned int* ghist = (unsigned int*)(w);
  int* cnt  = (int*)(w + 262144);
  int* tbin = (int*)(w + 262208);
  int* wcnt = (int*)(w + 262272);
  unsigned long long* cand = (unsigned long long*)(w + 262336);
  unsigned short* maxbin = (unsigned short*)(w + 262336 + 524288);       // 786624
  unsigned int* worklist = (unsigned int*)(w + 786624 + 806400);         // 1593024
  float* boxes8 = (float*)(w + 1593024 + 262144);                        // 1855168
  unsigned int* mat = (unsigned int*)(w + 1855168 + 512000);             // 2367168

  hipMemsetAsync(ghist, 0, 262144 + 192, stream);   // hist + cnt + tbin + wcnt

  k_passA<<<dim3(NIMG * TILES), dim3(256), 0, stream>>>(p0, p1, p2, ghist, maxbin);
  k_thresh<<<dim3(NIMG), dim3(256), 0, stream>>>(ghist, tbin);
  k_worklist<<<dim3((NIMG * NBOX + 255) / 256), dim3(256), 0, stream>>>(maxbin, tbin, worklist, wcnt);
  k_emit<<<dim3(256), dim3(256), 0, stream>>>(p0, p1, p2, worklist, wcnt, tbin, cand, cnt);
  k_sort<<<dim3(NIMG), dim3(256), 0, stream>>>(p0, p1, p2, anchors, cand, cnt, boxes8);
  k_iou<<<dim3(NIMG * (NTOP / IOU_RPB)), dim3(256), 0, stream>>>(boxes8, mat);
  k_nms<<<dim3(NIMG), dim3(64), 0, stream>>>(mat, boxes8, scalef, out);
}